// Round 5
// baseline (735.091 us; speedup 1.0000x reference)
//
#include <hip/hip_runtime.h>
#include <cstdint>

typedef unsigned short ushort_t;
typedef unsigned int uint_t;
typedef __attribute__((ext_vector_type(8))) short short8;   // 8 bf16 (4 VGPRs) - MFMA A/B frag
typedef __attribute__((ext_vector_type(4))) float f32x4;    // MFMA C/D frag

#define MFMA16(a, b, c) __builtin_amdgcn_mfma_f32_16x16x32_bf16((a), (b), (c), 0, 0, 0)
#define SWZ(c, r) ((((c) + ((r) >> 2)) & 3))
#define INV_N 1.9073486328125e-6f  // 1/524288

struct P4 { ushort_t* p[4]; };
struct B4 { const float* b[4]; };

__device__ __forceinline__ ushort_t f2bf(float f) {
    uint_t u = __builtin_bit_cast(uint_t, f);
    u += 0x7FFFu + ((u >> 16) & 1u);          // RNE
    return (ushort_t)(u >> 16);
}
__device__ __forceinline__ float bf2f(ushort_t h) {
    return __builtin_bit_cast(float, (uint_t)h << 16);
}

// ===================== weight prep (same layout as round 4) =====================
__global__ __launch_bounds__(256) void prep_w(
    ushort_t* wb, const float* qw, const float* kw, const float* vw,
    const float* ew1, const float* ew2, const float* sw1, const float* sw2,
    const float* bw1, const float* bw2,
    const float* scw, const float* b1w, const float* b2w)
{
    int idx = blockIdx.x * 256 + threadIdx.x;
    if (idx >= 663552) return;
    float v;
    if (idx < 49152) {
        int z = idx >> 14, r = idx & 16383;
        v = (z == 0 ? qw : z == 1 ? kw : vw)[r];
    } else if (idx < 122880) {
        int j = idx - 49152; int z = j / 36864; int jj = j - z * 36864;
        int o = jj / 288, k = jj - o * 288;
        v = (k < 277) ? (z ? ew2 : ew1)[o * 277 + k] : 0.f;
    } else if (idx < 155648) {
        int j = idx - 122880; int z = j >> 14;
        v = (z ? sw2 : sw1)[j & 16383];
    } else if (idx < 221184) {
        int j = idx - 155648; int z = j >> 15;
        v = (z ? bw2 : bw1)[j & 32767];
    } else {
        int j = idx - 221184;
        const float* src = j < 147456 ? scw : j < 294912 ? b1w : b2w;
        j = j % 147456;
        int tap = j >> 14, r = (j >> 7) & 127, c = j & 127;
        v = src[r * 1152 + c * 9 + tap];
    }
    wb[idx] = f2bf(v);
}

// ===================== combined aux weights: wc[z][128][288] =====================
__global__ __launch_bounds__(256) void combine_w(ushort_t* wc, const ushort_t* wb)
{
    __shared__ float ews[128 * 33];
    __shared__ ushort_t Ws[128 * 130];
    int z = blockIdx.y, nt = blockIdx.x, n0 = nt * 32;
    int t = threadIdx.x;
    const ushort_t* wew = wb + 49152;
    const ushort_t* wsw = wb + 122880;
    const ushort_t* wbw = wb + 155648;
    const ushort_t* W; int wstr, wof;
    if (z == 0)      { W = wsw;         wstr = 128; wof = 0; }
    else if (z == 1) { W = wbw;         wstr = 256; wof = 128; }
    else if (z == 2) { W = wsw + 16384; wstr = 128; wof = 0; }
    else             { W = wbw + 32768; wstr = 256; wof = 128; }
    const ushort_t* E = wew + (z >= 2 ? 36864 : 0);
    for (int s = t; s < 16384; s += 256) {
        int c = s & 127, o = s >> 7;
        Ws[c * 130 + o] = W[o * wstr + wof + c];
    }
    for (int s = t; s < 4096; s += 256) {
        int c = s >> 5, n = s & 31;
        ews[c * 33 + n] = bf2f(E[c * 288 + n0 + n]);
    }
    __syncthreads();
    int o = t & 127, nh = t >> 7;
    float acc[16];
#pragma unroll
    for (int i = 0; i < 16; ++i) acc[i] = 0.f;
    for (int c = 0; c < 128; ++c) {
        float wv = bf2f(Ws[c * 130 + o]);
#pragma unroll
        for (int i = 0; i < 16; ++i) acc[i] += wv * ews[c * 33 + nh * 16 + i];
    }
#pragma unroll
    for (int i = 0; i < 16; ++i)
        wc[(size_t)(z * 128 + o) * 288 + n0 + nh * 16 + i] = f2bf(acc[i]);
}

// combined biases bc[z][128] (fp32, from original fp32 params)
__global__ __launch_bounds__(512) void combine_bias(
    float* bc, const float* sw1, const float* bw1, const float* sw2, const float* bw2,
    const float* eb1, const float* eb2, const float* sb1, const float* bb1,
    const float* sb2, const float* bb2)
{
    int t = threadIdx.x; int z = t >> 7, o = t & 127;
    const float* W; int wstr, wof; const float* eb; float add;
    if (z == 0)      { W = sw1; wstr = 128; wof = 0;   eb = eb1; add = sb1[o]; }
    else if (z == 1) { W = bw1; wstr = 256; wof = 128; eb = eb1; add = bb1[o]; }
    else if (z == 2) { W = sw2; wstr = 128; wof = 0;   eb = eb2; add = sb2[o]; }
    else             { W = bw2; wstr = 256; wof = 128; eb = eb2; add = bb2[o]; }
    float s = add;
    for (int c = 0; c < 128; ++c) s += W[o * wstr + wof + c] * eb[c];
    bc[t] = s;
}

// ===================== x transpose: f32 [b][128][4096] -> bf16 [b][4096][128] ==========
__global__ __launch_bounds__(256) void transp_x(const float* __restrict__ x, ushort_t* __restrict__ xT)
{
    __shared__ ushort_t tile[64 * 130];
    int b = blockIdx.y, p0 = blockIdx.x * 64;
    int t = threadIdx.x;
#pragma unroll
    for (int i = 0; i < 8; ++i) {
        int s = t + i * 256;
        int c = s >> 4, p4 = (s & 15) * 4;
        float4 f = *(const float4*)(x + ((size_t)(b * 128 + c) << 12) + p0 + p4);
        tile[(p4 + 0) * 130 + c] = f2bf(f.x);
        tile[(p4 + 1) * 130 + c] = f2bf(f.y);
        tile[(p4 + 2) * 130 + c] = f2bf(f.z);
        tile[(p4 + 3) * 130 + c] = f2bf(f.w);
    }
    __syncthreads();
#pragma unroll
    for (int i = 0; i < 4; ++i) {
        int s = t + i * 256;
        int p = s >> 4, c8 = (s & 15) * 8;
        ushort_t v[8];
#pragma unroll
        for (int e = 0; e < 8; ++e) v[e] = tile[p * 130 + c8 + e];
        uint4 ov = {(uint_t)v[0] | ((uint_t)v[1] << 16), (uint_t)v[2] | ((uint_t)v[3] << 16),
                    (uint_t)v[4] | ((uint_t)v[5] << 16), (uint_t)v[6] | ((uint_t)v[7] << 16)};
        *(uint4*)(xT + ((size_t)(b * 4096) + p0 + p) * 128 + c8) = ov;
    }
}

// ===================== aux concat+transpose -> bf16 [b][4096][288] ==========
__global__ __launch_bounds__(256) void transp_aux(const float* __restrict__ edge, const float* __restrict__ seg,
                                                  const float* __restrict__ pe, const float* __restrict__ ps,
                                                  ushort_t* __restrict__ auxT)
{
    __shared__ ushort_t tile[64 * 292];
    int b = blockIdx.y, p0 = blockIdx.x * 64;
    int t = threadIdx.x;
#pragma unroll
    for (int i = 0; i < 18; ++i) {
        int s = t + i * 256;
        int c = s >> 4, p4 = (s & 15) * 4;
        float4 f = {0.f, 0.f, 0.f, 0.f};
        if (c < 128)       f = *(const float4*)(edge + ((size_t)(b * 128 + c) << 12) + p0 + p4);
        else if (c < 256)  f = *(const float4*)(seg + ((size_t)(b * 128 + c - 128) << 12) + p0 + p4);
        else if (c == 256) f = *(const float4*)(pe + ((size_t)b << 12) + p0 + p4);
        else if (c < 277)  f = *(const float4*)(ps + ((size_t)(b * 20 + c - 257) << 12) + p0 + p4);
        tile[(p4 + 0) * 292 + c] = f2bf(f.x);
        tile[(p4 + 1) * 292 + c] = f2bf(f.y);
        tile[(p4 + 2) * 292 + c] = f2bf(f.z);
        tile[(p4 + 3) * 292 + c] = f2bf(f.w);
    }
    __syncthreads();
#pragma unroll
    for (int i = 0; i < 9; ++i) {
        int s = t + i * 256;
        int p = s / 36, c8 = (s % 36) * 8;
        ushort_t v[8];
#pragma unroll
        for (int e = 0; e < 8; ++e) v[e] = tile[p * 292 + c8 + e];
        uint4 ov = {(uint_t)v[0] | ((uint_t)v[1] << 16), (uint_t)v[2] | ((uint_t)v[3] << 16),
                    (uint_t)v[4] | ((uint_t)v[5] << 16), (uint_t)v[6] | ((uint_t)v[7] << 16)};
        *(uint4*)(auxT + ((size_t)(b * 4096) + p0 + p) * 288 + c8) = ov;
    }
}

// ===================== stacked multi-slice GEMM: C[128p][NS*128och] =====================
// A (LDS low) = stacked weights Wstk[NS*128][K]; B (LDS high) = activations [128p][K].
// Activation tile read ONCE for all NS output slices (was NS separate z-dispatches).
// Per-slice coalesced LDS epilogue with bias + optional LN stats.
template <int NS, int DOSTATS>
__global__ __launch_bounds__(NS * 256) void gemm_stack(
    const ushort_t* __restrict__ bA, int K, const ushort_t* __restrict__ Wstk, int NK,
    B4 bias4, P4 out4, float* stats)
{
    constexpr int STAGE = NS * 8192 + 8192;
    constexpr int LDSZ = (STAGE > 34816) ? STAGE : 34816;
    __shared__ char lds[LDSZ];
    int b = blockIdx.y, bx = blockIdx.x;
    int t = threadIdx.x, lane = t & 63, w = t >> 6;
    int wm = w >> 1, wn = w & 1, lo = lane & 15, quad = lane >> 4;
    size_t bbase = (size_t)b * 4096;

    f32x4 acc[4][4];
#pragma unroll
    for (int i = 0; i < 4; ++i)
#pragma unroll
        for (int j = 0; j < 4; ++j) acc[i][j] = (f32x4){0.f, 0.f, 0.f, 0.f};

    const int TOT = (NS + 1) * 512;
    uint4 pf[3];
#pragma unroll
    for (int i = 0; i < 3; ++i) {
        int s = t + i * NS * 256;
        if (s < TOT) {
            if (s < NS * 512) { int q = s >> 2, c = s & 3; pf[i] = *(const uint4*)(Wstk + (size_t)q * K + c * 8); }
            else { int r = (s - NS * 512) >> 2, c = s & 3; pf[i] = *(const uint4*)(bA + (bbase + bx * 128 + r) * (size_t)K + c * 8); }
        }
    }
    for (int ck = 0; ck < NK; ++ck) {
        __syncthreads();
#pragma unroll
        for (int i = 0; i < 3; ++i) {
            int s = t + i * NS * 256;
            if (s < TOT) {
                int off;
                if (s < NS * 512) { int q = s >> 2, c = s & 3; off = q * 64 + SWZ(c, q) * 16; }
                else { int r = (s - NS * 512) >> 2, c = s & 3; off = NS * 8192 + r * 64 + SWZ(c, r) * 16; }
                *(uint4*)(lds + off) = pf[i];
            }
        }
        __syncthreads();
        if (ck + 1 < NK) {
            int k0 = (ck + 1) * 32;
#pragma unroll
            for (int i = 0; i < 3; ++i) {
                int s = t + i * NS * 256;
                if (s < TOT) {
                    if (s < NS * 512) { int q = s >> 2, c = s & 3; pf[i] = *(const uint4*)(Wstk + (size_t)q * K + k0 + c * 8); }
                    else { int r = (s - NS * 512) >> 2, c = s & 3; pf[i] = *(const uint4*)(bA + (bbase + bx * 128 + r) * (size_t)K + k0 + c * 8); }
                }
            }
        }
        short8 af[4];
#pragma unroll
        for (int mt = 0; mt < 4; ++mt) {
            int row = wm * 64 + mt * 16 + lo;
            af[mt] = *(const short8*)(lds + row * 64 + SWZ(quad, row) * 16);
        }
#pragma unroll
        for (int nt = 0; nt < 4; ++nt) {
            int n = wn * 64 + nt * 16 + lo;
            short8 bf = *(const short8*)(lds + NS * 8192 + n * 64 + SWZ(quad, n) * 16);
#pragma unroll
            for (int mt = 0; mt < 4; ++mt) acc[mt][nt] = MFMA16(af[mt], bf, acc[mt][nt]);
        }
    }

    // per-slice epilogue: stage [pp][136] in LDS, coalesced copy-out
    ushort_t* Cs = (ushort_t*)lds;
    for (int z = 0; z < NS; ++z) {
        __syncthreads();
        if ((wm >> 1) == z) {
            float lsum = 0.f, lss = 0.f;
#pragma unroll
            for (int mt = 0; mt < 4; ++mt)
#pragma unroll
                for (int nt = 0; nt < 4; ++nt) {
                    int oo0 = (wm & 1) * 64 + mt * 16 + quad * 4;
                    int pp = wn * 64 + nt * 16 + lo;
                    float vv[4];
#pragma unroll
                    for (int r = 0; r < 4; ++r) vv[r] = acc[mt][nt][r] + bias4.b[z][oo0 + r];
                    if (DOSTATS) {
#pragma unroll
                        for (int r = 0; r < 4; ++r) { lsum += vv[r]; lss += vv[r] * vv[r]; }
                    }
                    ushort4 st = {f2bf(vv[0]), f2bf(vv[1]), f2bf(vv[2]), f2bf(vv[3])};
                    *(ushort4*)(&Cs[pp * 136 + oo0]) = st;
                }
            if (DOSTATS) {
#pragma unroll
                for (int o2 = 32; o2 >= 1; o2 >>= 1) { lsum += __shfl_xor(lsum, o2); lss += __shfl_xor(lss, o2); }
                if (lane == 0) {
                    atomicAdd(&stats[(z * 16 + b) * 2], lsum);
                    atomicAdd(&stats[(z * 16 + b) * 2 + 1], lss);
                }
            }
        }
        __syncthreads();
        ushort_t* outp = out4.p[z];
#pragma unroll
        for (int i = 0; i < 3; ++i) {
            int c3 = t + i * NS * 256;
            if (c3 < 2048) {
                int pp = c3 >> 4, ii = c3 & 15;
                *(uint4*)(outp + (bbase + bx * 128 + pp) * 128 + ii * 8) = *(const uint4*)(&Cs[pp * 136 + ii * 8]);
            }
        }
    }
}

// ===================== conv1x1-family MFMA GEMM =====================
// EP 2: ADN1: v=acc + betT + (tin-mu)*rstd*gT; patch scatter
// EP 3: ADN2: same math, QUARTERED out [b*4+cc][p][32] (for conv staging)
template <int EP>
__global__ __launch_bounds__(256) void gemm_conv(
    const ushort_t* bA, int Kb1, size_t zBoff,
    const ushort_t* wA, int wstride, int wAperZ, int NK,
    B4 bias4, P4 out4, const ushort_t* gT, const ushort_t* betT,
    float* stats, int dostats)
{
    constexpr int LDSZ = (EP == 2) ? 33792 : 34816;
    __shared__ char lds[LDSZ];
    int b = blockIdx.y, bx = blockIdx.x, z = blockIdx.z;
    int t = threadIdx.x, lane = t & 63, w = t >> 6;
    int wm = w & 1, wn = w >> 1, lo = lane & 15, quad = lane >> 4;
    const ushort_t* wAz = wA + (wAperZ ? (size_t)z * 128 * wstride : 0);
    const ushort_t* bAz = bA + (size_t)z * zBoff;
    ushort_t* outp = out4.p[z];
    size_t bbase = (size_t)b * 4096;
    int y0 = 0, x0 = 0;
    if (EP == 2) { y0 = (bx >> 1) * 4; x0 = (bx & 1) * 32; }

    f32x4 acc[4][4];
#pragma unroll
    for (int i = 0; i < 4; ++i)
#pragma unroll
        for (int j = 0; j < 4; ++j) acc[i][j] = (f32x4){0.f, 0.f, 0.f, 0.f};

    int r0 = t >> 2, c0 = t & 3, r1 = r0 + 64;
    int gp0, gp1;
    if (EP == 2) {
        gp0 = (y0 + (r0 >> 5)) * 64 + x0 + (r0 & 31);
        gp1 = (y0 + (r1 >> 5)) * 64 + x0 + (r1 & 31);
    } else {
        gp0 = bx * 128 + r0;
        gp1 = bx * 128 + r1;
    }
    const ushort_t* bRow0 = bAz + (bbase + gp0) * Kb1;
    const ushort_t* bRow1 = bAz + (bbase + gp1) * Kb1;
    uint4 pfA0 = *(const uint4*)(wAz + (size_t)r0 * wstride + c0 * 8);
    uint4 pfA1 = *(const uint4*)(wAz + (size_t)r1 * wstride + c0 * 8);
    uint4 pfB0 = *(const uint4*)(bRow0 + c0 * 8);
    uint4 pfB1 = *(const uint4*)(bRow1 + c0 * 8);
    for (int ck = 0; ck < NK; ++ck) {
        __syncthreads();
        *(uint4*)(lds + r0 * 64 + SWZ(c0, r0) * 16) = pfA0;
        *(uint4*)(lds + r1 * 64 + SWZ(c0, r1) * 16) = pfA1;
        *(uint4*)(lds + 8192 + r0 * 64 + SWZ(c0, r0) * 16) = pfB0;
        *(uint4*)(lds + 8192 + r1 * 64 + SWZ(c0, r1) * 16) = pfB1;
        __syncthreads();
        if (ck + 1 < NK) {
            int k0 = (ck + 1) * 32;
            pfA0 = *(const uint4*)(wAz + (size_t)r0 * wstride + k0 + c0 * 8);
            pfA1 = *(const uint4*)(wAz + (size_t)r1 * wstride + k0 + c0 * 8);
            pfB0 = *(const uint4*)(bRow0 + k0 + c0 * 8);
            pfB1 = *(const uint4*)(bRow1 + k0 + c0 * 8);
        }
        short8 af[4];
#pragma unroll
        for (int mt = 0; mt < 4; ++mt) {
            int row = wm * 64 + mt * 16 + lo;
            af[mt] = *(const short8*)(lds + row * 64 + SWZ(quad, row) * 16);
        }
#pragma unroll
        for (int nt = 0; nt < 4; ++nt) {
            int n = wn * 64 + nt * 16 + lo;
            short8 bf = *(const short8*)(lds + 8192 + n * 64 + SWZ(quad, n) * 16);
#pragma unroll
            for (int mt = 0; mt < 4; ++mt) acc[mt][nt] = MFMA16(af[mt], bf, acc[mt][nt]);
        }
    }

    float mean = 0.f, rstd = 0.f;
    {
        int slot = (EP == 3) ? 3 : z;
        float s0 = stats[(slot * 16 + b) * 2], s1 = stats[(slot * 16 + b) * 2 + 1];
        mean = s0 * INV_N;
        rstd = rsqrtf(fmaxf(s1 * INV_N - mean * mean, 0.f) + 1e-5f);
    }
    if (EP == 2) {
        __syncthreads();
        ushort_t* Cs = (ushort_t*)lds;
#pragma unroll
        for (int mt = 0; mt < 4; ++mt)
#pragma unroll
            for (int nt = 0; nt < 4; ++nt) {
                int oo0 = wm * 64 + mt * 16 + quad * 4;
                int pp = wn * 64 + nt * 16 + lo;
                int gp = (y0 + (pp >> 5)) * 64 + x0 + (pp & 31);
                size_t tbase = (bbase + gp) * 128 + oo0;
                ushort4 tv = *(const ushort4*)(bAz + tbase);
                ushort4 gv = *(const ushort4*)(gT + tbase);
                ushort4 bv = *(const ushort4*)(betT + tbase);
#pragma unroll
                for (int r = 0; r < 4; ++r) {
                    float v = acc[mt][nt][r] + bf2f((&bv.x)[r])
                            + (bf2f((&tv.x)[r]) - mean) * rstd * bf2f((&gv.x)[r]);
                    Cs[(oo0 + r) * 132 + pp] = f2bf(v);
                }
            }
        __syncthreads();
        if (z < 2) {
            // half0 [n][256]: full 512B rows
            for (int s = t; s < 1024; s += 256) {
                int n_l = s >> 5, fq = s & 31;
                int ypair = n_l >> 4, xp = n_l & 15;
                ushort_t tmp[8];
#pragma unroll
                for (int e = 0; e < 8; ++e) {
                    int f = fq * 8 + e;
                    int c = f >> 2, py = (f >> 1) & 1, px = f & 1;
                    tmp[e] = Cs[c * 132 + (ypair * 2 + py) * 32 + xp * 2 + px];
                }
                int n = ((y0 >> 1) + ypair) * 32 + (x0 >> 1) + xp;
                uint4 ov = {(uint_t)tmp[0] | ((uint_t)tmp[1] << 16), (uint_t)tmp[2] | ((uint_t)tmp[3] << 16),
                            (uint_t)tmp[4] | ((uint_t)tmp[5] << 16), (uint_t)tmp[6] | ((uint_t)tmp[7] << 16)};
                *(uint4*)(outp + ((size_t)(b * 1024 + n) << 8) + fq * 8) = ov;
            }
            // half1 [n][1024]: full 2KB rows
            for (int s = t; s < 1024; s += 256) {
                int n_l = s >> 7, fq = s & 127;
                ushort_t tmp[8];
#pragma unroll
                for (int e = 0; e < 8; ++e) {
                    int f = fq * 8 + e;
                    int c = f >> 4, py = (f >> 2) & 3, px = f & 3;
                    tmp[e] = Cs[(64 + c) * 132 + py * 32 + n_l * 4 + px];
                }
                int n = (y0 >> 2) * 16 + (x0 >> 2) + n_l;
                uint4 ov = {(uint_t)tmp[0] | ((uint_t)tmp[1] << 16), (uint_t)tmp[2] | ((uint_t)tmp[3] << 16),
                            (uint_t)tmp[4] | ((uint_t)tmp[5] << 16), (uint_t)tmp[6] | ((uint_t)tmp[7] << 16)};
                *(uint4*)(outp + 4194304u + ((size_t)(b * 256 + n) << 10) + fq * 8) = ov;
            }
        } else {
            // VT half0 [f=256][m=1024]
            for (int s = t; s < 2048; s += 256) {
                int f = s >> 3, j = s & 7;
                int ypair = j >> 2, xq = j & 3;
                int c = f >> 2, py = (f >> 1) & 1, px = f & 1;
                ushort_t tmp[4];
#pragma unroll
                for (int i2 = 0; i2 < 4; ++i2)
                    tmp[i2] = Cs[c * 132 + (ypair * 2 + py) * 32 + (xq * 4 + i2) * 2 + px];
                int m0 = ((y0 >> 1) + ypair) * 32 + (x0 >> 1) + xq * 4;
                uint2 ov = {(uint_t)tmp[0] | ((uint_t)tmp[1] << 16), (uint_t)tmp[2] | ((uint_t)tmp[3] << 16)};
                *(uint2*)(outp + ((size_t)(b * 256 + f) << 10) + m0) = ov;
            }
            // VT half1 [f=1024][m=256]
            for (int s = t; s < 2048; s += 256) {
                int f = s >> 1, j = s & 1;
                int c = f >> 4, py = (f >> 2) & 3, px = f & 3;
                ushort_t tmp[4];
#pragma unroll
                for (int i2 = 0; i2 < 4; ++i2)
                    tmp[i2] = Cs[(64 + c) * 132 + py * 32 + (j * 4 + i2) * 4 + px];
                int m0 = (y0 >> 2) * 16 + (x0 >> 2) + j * 4;
                uint2 ov = {(uint_t)tmp[0] | ((uint_t)tmp[1] << 16), (uint_t)tmp[2] | ((uint_t)tmp[3] << 16)};
                *(uint2*)(outp + 4194304u + ((size_t)(b * 1024 + f) << 8) + m0) = ov;
            }
        }
    } else {
        // EP3: stage C-tile in LDS as [pp][136ch] then copy out quartered
        ushort_t* Cs = (ushort_t*)lds;
        __syncthreads();
#pragma unroll
        for (int mt = 0; mt < 4; ++mt)
#pragma unroll
            for (int nt = 0; nt < 4; ++nt) {
                int oo0 = wm * 64 + mt * 16 + quad * 4;
                int pp = wn * 64 + nt * 16 + lo;
                float vv[4];
                size_t tbase = (bbase + bx * 128 + pp) * 128 + oo0;
                ushort4 tv = *(const ushort4*)(bAz + tbase);
                ushort4 gv = *(const ushort4*)(gT + tbase);
                ushort4 bv = *(const ushort4*)(betT + tbase);
#pragma unroll
                for (int r = 0; r < 4; ++r)
                    vv[r] = acc[mt][nt][r] + bf2f((&bv.x)[r])
                          + (bf2f((&tv.x)[r]) - mean) * rstd * bf2f((&gv.x)[r]);
                ushort4 st = {f2bf(vv[0]), f2bf(vv[1]), f2bf(vv[2]), f2bf(vv[3])};
                *(ushort4*)(&Cs[pp * 136 + oo0]) = st;
            }
        __syncthreads();
        // quartered out: [b*4+cc][4096][32]
#pragma unroll
        for (int i = 0; i < 2; ++i) {
            int c = t + i * 256;
            int cc2 = c >> 7, pp = c & 127;
            size_t dst = ((size_t)(b * 4 + cc2) * 4096 + bx * 128 + pp) * 32;
#pragma unroll
            for (int j = 0; j < 4; ++j)
                *(uint4*)(outp + dst + j * 8) = *(const uint4*)(&Cs[pp * 136 + cc2 * 32 + j * 8]);
        }
    }
}

// ===================== attention batched MFMA GEMM ===============
// EP0 stages S through LDS (col-major) for fully coalesced row writes.
template <int EP>
__global__ __launch_bounds__(256) void gemm_attn(
    const ushort_t* A, size_t aBS, const ushort_t* Bm, size_t bBS,
    int Ka, int NK, float scale,
    ushort_t* sout, size_t soBS, int soNb,
    const ushort_t* xT, ushort_t* midT, float* stats)
{
    constexpr int LDSZ = (EP >= 1) ? 33792 : 34816;
    __shared__ char lds[LDSZ];
    int b = blockIdx.z, my = blockIdx.y, nx = blockIdx.x;
    int t = threadIdx.x, lane = t & 63, w = t >> 6;
    int wm = w & 1, wn = w >> 1, lo = lane & 15, quad = lane >> 4;

    f32x4 acc[4][4];
#pragma unroll
    for (int i = 0; i < 4; ++i)
#pragma unroll
        for (int j = 0; j < 4; ++j) acc[i][j] = (f32x4){0.f, 0.f, 0.f, 0.f};

    const ushort_t* Ab = A + b * aBS + (size_t)(my * 128) * Ka;
    const ushort_t* Bb = Bm + b * bBS + (size_t)(nx * 128) * Ka;
    int r0 = t >> 2, c0 = t & 3, r1 = r0 + 64;
    uint4 pfA0 = *(const uint4*)(Ab + (size_t)r0 * Ka + c0 * 8);
    uint4 pfA1 = *(const uint4*)(Ab + (size_t)r1 * Ka + c0 * 8);
    uint4 pfB0 = *(const uint4*)(Bb + (size_t)r0 * Ka + c0 * 8);
    uint4 pfB1 = *(const uint4*)(Bb + (size_t)r1 * Ka + c0 * 8);
    for (int ck = 0; ck < NK; ++ck) {
        __syncthreads();
        *(uint4*)(lds + r0 * 64 + SWZ(c0, r0) * 16) = pfA0;
        *(uint4*)(lds + r1 * 64 + SWZ(c0, r1) * 16) = pfA1;
        *(uint4*)(lds + 8192 + r0 * 64 + SWZ(c0, r0) * 16) = pfB0;
        *(uint4*)(lds + 8192 + r1 * 64 + SWZ(c0, r1) * 16) = pfB1;
        __syncthreads();
        if (ck + 1 < NK) {
            int k0 = (ck + 1) * 32;
            pfA0 = *(const uint4*)(Ab + (size_t)r0 * Ka + k0 + c0 * 8);
            pfA1 = *(const uint4*)(Ab + (size_t)r1 * Ka + k0 + c0 * 8);
            pfB0 = *(const uint4*)(Bb + (size_t)r0 * Ka + k0 + c0 * 8);
            pfB1 = *(const uint4*)(Bb + (size_t)r1 * Ka + k0 + c0 * 8);
        }
        short8 af[4];
#pragma unroll
        for (int mt = 0; mt < 4; ++mt) {
            int row = wm * 64 + mt * 16 + lo;
            af[mt] = *(const short8*)(lds + row * 64 + SWZ(quad, row) * 16);
        }
#pragma unroll
        for (int nt = 0; nt < 4; ++nt) {
            int n = wn * 64 + nt * 16 + lo;
            short8 bf = *(const short8*)(lds + 8192 + n * 64 + SWZ(quad, n) * 16);
#pragma unroll
            for (int mt = 0; mt < 4; ++mt) acc[mt][nt] = MFMA16(af[mt], bf, acc[mt][nt]);
        }
    }

    if (EP == 0) {
        // stage col-major: Cs[c][136 + r]
        ushort_t* Cs = (ushort_t*)lds;
        __syncthreads();
#pragma unroll
        for (int mt = 0; mt < 4; ++mt)
#pragma unroll
            for (int nt = 0; nt < 4; ++nt) {
                int rr0 = wm * 64 + mt * 16 + quad * 4;
                int cl = wn * 64 + nt * 16 + lo;
                ushort4 st = {f2bf(acc[mt][nt][0] * scale), f2bf(acc[mt][nt][1] * scale),
                              f2bf(acc[mt][nt][2] * scale), f2bf(acc[mt][nt][3] * scale)};
                *(ushort4*)(&Cs[cl * 136 + rr0]) = st;
            }
        __syncthreads();
        {
            int rr = t >> 1, hf = t & 1;
            size_t gbase = (size_t)b * soBS + (size_t)(my * 128 + rr) * soNb + nx * 128 + hf * 64;
#pragma unroll
            for (int i = 0; i < 8; ++i) {
                ushort_t e[8];
#pragma unroll
                for (int j = 0; j < 8; ++j) e[j] = Cs[(hf * 64 + i * 8 + j) * 136 + rr];
                uint4 ov = {(uint_t)e[0] | ((uint_t)e[1] << 16), (uint_t)e[2] | ((uint_t)e[3] << 16),
                            (uint_t)e[4] | ((uint_t)e[5] << 16), (uint_t)e[6] | ((uint_t)e[7] << 16)};
                *(uint4*)(sout + gbase + i * 8) = ov;
            }
        }
        return;
    }
    __syncthreads();
    ushort_t* Cs = (ushort_t*)lds;
#pragma unroll
    for (int mt = 0; mt < 4; ++mt)
#pragma unroll
        for (int nt = 0; nt < 4; ++nt)
#pragma unroll
            for (int reg = 0; reg < 4; ++reg) {
                int r_l = wm * 64 + mt * 16 + quad * 4 + reg;
                int c_l = wn * 64 + nt * 16 + lo;
                Cs[r_l * 132 + c_l] = f2bf(acc[mt][nt][reg]);
            }
    __syncthreads();
    float lsum = 0.f, lss = 0.f;
    for (int s = t; s < 4096; s += 256) {
        int sp, r_l, cbase, pybit, pxbit;
        if (EP == 1) {
            int sp_l = s >> 3, cj = s & 7;
            int y_l = sp_l >> 6, xv = sp_l & 63;
            r_l = (y_l >> 1) * 32 + (xv >> 1);
            sp = (my * 8 + y_l) * 64 + xv;
            cbase = nx * 32 + cj * 4;
            pybit = (y_l & 1) * 2 + (xv & 1);
            pxbit = 4;
        } else {
            int sp_l = s >> 1, cj = s & 1;
            int y_l = sp_l >> 6, xv = sp_l & 63;
            r_l = (y_l >> 2) * 16 + (xv >> 2);
            sp = (my * 32 + y_l) * 64 + xv;
            cbase = 64 + nx * 8 + cj * 4;
            pybit = (y_l & 3) * 4 + (xv & 3);
            pxbit = 16;
        }
        size_t base = ((size_t)(b * 4096) + sp) * 128 + cbase;
        ushort4 xv4 = *(const ushort4*)(xT + base);
        int c_l0 = (EP == 1) ? (cbase - nx * 32) * 4 + pybit : (cbase - 64 - nx * 8) * 16 + pybit;
        ushort_t o4[4];
#pragma unroll
        for (int ci = 0; ci < 4; ++ci) {
            float vm = bf2f(Cs[r_l * 132 + c_l0 + ci * pxbit]) + bf2f((&xv4.x)[ci]);
            o4[ci] = f2bf(vm);
            lsum += vm; lss += vm * vm;
        }
        ushort4 st = {o4[0], o4[1], o4[2], o4[3]};
        *(ushort4*)(midT + base) = st;
    }
#pragma unroll
    for (int o2 = 32; o2 >= 1; o2 >>= 1) { lsum += __shfl_xor(lsum, o2); lss += __shfl_xor(lss, o2); }
    __syncthreads();
    float* red = (float*)lds;
    if (lane == 0) { red[w * 2] = lsum; red[w * 2 + 1] = lss; }
    __syncthreads();
    if (t == 0) {
        atomicAdd(&stats[(3 * 16 + b) * 2], red[0] + red[2] + red[4] + red[6]);
        atomicAdd(&stats[(3 * 16 + b) * 2 + 1], red[1] + red[3] + red[5] + red[7]);
    }
}

// ===================== softmax (in-place bf16 S -> P) =====================
__global__ __launch_bounds__(256) void softmax_k(ushort_t* SP)
{
    int wid = blockIdx.x * 4 + (threadIdx.x >> 6);
    int lane = threadIdx.x & 63;
    ushort_t* row;
    int PL;
    if (wid < 16384) { row = SP + ((size_t)wid << 10); PL = 16; }
    else { int r2 = wid - 16384; row = SP + 16777216u + ((size_t)r2 << 8); PL = 4; }
    float v[16];
    float mx = -1e30f;
    for (int i = 0; i < PL; ++i) { v[i] = bf2f(row[lane + (i << 6)]); mx = fmaxf(mx, v[i]); }
#pragma unroll
    for (int o = 32; o >= 1; o >>= 1) mx = fmaxf(mx, __shfl_xor(mx, o));
    float sum = 0.f;
    for (int i = 0; i < PL; ++i) { v[i] = __expf(v[i] - mx); sum += v[i]; }
#pragma unroll
    for (int o = 32; o >= 1; o >>= 1) sum += __shfl_xor(sum, o);
    float inv = 1.f / sum;
    for (int i = 0; i < PL; ++i) row[lane + (i << 6)] = f2bf(v[i] * inv);
}

// ===================== conv3x3 dual (tanh DIL1 / gelu DIL2 via z) =====================
// input oT QUARTERED [b*4+cc][4096][32]; z=0 out (g3) [p][128]; z=1 out (tT) QUARTERED.
__global__ __launch_bounds__(1024) void conv3x3_dual(
    const ushort_t* __restrict__ inT, const ushort_t* __restrict__ wtA, const ushort_t* __restrict__ wtB,
    const float* __restrict__ biasA, const float* __restrict__ biasB,
    ushort_t* __restrict__ outA, ushort_t* __restrict__ outB)
{
    __shared__ char lds[73728 + 12 * 68 * 64];
    char* Braw = lds + 73728;
    int b = blockIdx.y, z = blockIdx.z;
    int dil = 1 + z;
    int NRr = 8 + 2 * dil;
    const ushort_t* wt = z ? wtB : wtA;
    const float* bias = z ? biasB : biasA;
    ushort_t* out = z ? outB : outA;
    int y0 = blockIdx.x * 8;
    int t = threadIdx.x, lane = t & 63, w = t >> 6;
    int wm = w & 1, wr = w >> 1, lo = lane & 15, quad = lane >> 4;

    f32x4 acc[4][4];
#pragma unroll
    for (int i = 0; i < 4; ++i)
#pragma unroll
        for (int j = 0; j < 4; ++j) acc[i][j] = (f32x4){0.f, 0.f, 0.f, 0.f};

    for (int cc = 0; cc < 4; ++cc) {
        if (cc) __syncthreads();
        for (int s = t; s < 4608; s += 1024) {
            int tap = s >> 9, r = (s >> 2) & 127, c = s & 3;
            uint4 v = *(const uint4*)(wt + ((size_t)(tap * 128 + r) << 7) + cc * 32 + c * 8);
            *(uint4*)(lds + tap * 8192 + r * 64 + SWZ(c, r) * 16) = v;
        }
        int NSLOT = NRr * 272;
        for (int s = t; s < NSLOT; s += 1024) {
            int c4 = s & 3;
            int pr = s >> 2;
            int xx = pr % 68, rr = pr / 68;
            int ys = y0 - dil + rr;
            int ix = xx - dil;
            uint4 v = {0u, 0u, 0u, 0u};
            if (ys >= 0 && ys < 64 && (unsigned)ix < 64u)
                v = *(const uint4*)(inT + ((size_t)((b * 4 + cc) * 4096 + ys * 64 + ix)) * 32 + c4 * 8);
            *(uint4*)(Braw + pr * 64 + SWZ(c4, pr) * 16) = v;
        }
        __syncthreads();
#pragma unroll
        for (int tap = 0; tap < 9; ++tap) {
            int ky = tap / 3, kx = tap % 3;
            short8 af[4];
#pragma unroll
            for (int mt = 0; mt < 4; ++mt) {
                int row = wm * 64 + mt * 16 + lo;
                af[mt] = *(const short8*)(lds + tap * 8192 + row * 64 + SWZ(quad, row) * 16);
            }
#pragma unroll
            for (int nt = 0; nt < 4; ++nt) {
                int pr = (wr + ky * dil) * 68 + nt * 16 + lo + kx * dil;
                short8 bf = *(const short8*)(Braw + pr * 64 + SWZ(quad, pr) * 16);
#pragma unroll
                for (int mt = 0; mt < 4; ++mt) acc[mt][nt] = MFMA16(af[mt], bf, acc[mt][nt]);
            }
        }
    }
    // coalesced epilogue: two halves of 4 rows each, staged in LDS then linear copy-out
    for (int h = 0; h < 2; ++h) {
        __syncthreads();
        if ((wr >> 2) == h) {
            int rl = wr & 3;
#pragma unroll
            for (int mt = 0; mt < 4; ++mt)
#pragma unroll
                for (int nt = 0; nt < 4; ++nt) {
                    int oo0 = wm * 64 + mt * 16 + quad * 4;
                    int col = nt * 16 + lo;
                    ushort4 st;
#pragma unroll
                    for (int r = 0; r < 4; ++r) {
                        float v = acc[mt][nt][r] + bias[oo0 + r];
                        if (z == 0) v = tanhf(v);
                        else        v = 0.5f * v * (1.f + erff(v * 0.70710678118654752f));
                        (&st.x)[r] = f2bf(v);
                    }
                    int byo = ((rl * 64 + col) * 256 + oo0 * 2) ^ ((col & 15) << 4);
                    *(ushort4*)(lds + byo) = st;
                }
        }
        __syncthreads();
        if (z == 0) {
            int rl2 = t >> 8, col2 = (t >> 2) & 63, k2 = t & 3;
            char* dst = (char*)out + (((size_t)(b * 4096) + (y0 + h * 4 + rl2) * 64 + col2) << 8) + k2 * 64;
            int bb = (rl2 * 64 + col2) * 256 + k2 * 64;
            int sw = (col2 & 15) << 4;
#pragma unroll
            for (int i = 0; i < 4; ++i)
                *(uint4*)(dst + i * 16) = *(const uint4*)(lds + ((bb + i * 16) ^ sw));
        } else {
            int cc2 = t >> 8, s_l = t & 255;
            int rl2 = s_l >> 6, col2 = s_l & 63;
            ushort_t* dst = out + ((size_t)((b * 4 + cc2) * 4096) + (y0 + h * 4 + rl2) * 64 + col2) * 32;
            int bb = (rl2 * 64 + col2) * 256 + cc2 * 64;
            int sw = (col2 & 15) << 4;
#pragma unroll
            for (int i = 0; i < 4; ++i)
                *(uint4*)(dst + i * 8) = *(const uint4*)(lds + ((bb + i * 16) ^ sw));
        }
    }
}

// ===================== conv3x3 final: midT*g3T + conv(tT) -> f32 [b][c][p] ==============
// input tT QUARTERED [b*4+cc][4096][32].
__global__ __launch_bounds__(512) void conv3x3_final(
    const ushort_t* __restrict__ inT, const ushort_t* __restrict__ wt, const float* __restrict__ bias,
    float* __restrict__ out, const ushort_t* __restrict__ midT, const ushort_t* __restrict__ g3T)
{
    __shared__ char lds[73728 + 6 * 68 * 64];
    char* Braw = lds + 73728;
    int b = blockIdx.y;
    int y0 = blockIdx.x * 4;
    int t = threadIdx.x, lane = t & 63, w = t >> 6;
    int wm = w & 1, wr = w >> 1, lo = lane & 15, quad = lane >> 4;

    f32x4 acc[4][4];
#pragma unroll
    for (int i = 0; i < 4; ++i)
#pragma unroll
        for (int j = 0; j < 4; ++j) acc[i][j] = (f32x4){0.f, 0.f, 0.f, 0.f};

    for (int cc = 0; cc < 4; ++cc) {
        if (cc) __syncthreads();
        for (int s = t; s < 4608; s += 512) {
            int tap = s >> 9, r = (s >> 2) & 127, c = s & 3;
            uint4 v = *(const uint4*)(wt + ((size_t)((tap)*128 + r) << 7) + cc * 32 + c * 8);
            *(uint4*)(lds + tap * 8192 + r * 64 + SWZ(c, r) * 16) = v;
        }
        for (int s = t; s < 1632; s += 512) {
            int c4 = s & 3;
            int pr = s >> 2;
            int xx = pr % 68, rr = pr / 68;
            int ys = y0 - 1 + rr;
            int ix = xx - 1;
            uint4 v = {0u, 0u, 0u, 0u};
            if (ys >= 0 && ys < 64 && (unsigned)ix < 64u)
                v = *(const uint4*)(inT + ((size_t)((b * 4 + cc) * 4096 + ys * 64 + ix)) * 32 + c4 * 8);
            *(uint4*)(Braw + pr * 64 + SWZ(c4, pr) * 16) = v;
        }
        __syncthreads();
#pragma unroll
        for (int tap = 0; tap < 9; ++tap) {
            int ky = tap / 3, kx = tap % 3;
            short8 af[4];
#pragma unroll
            for (int mt = 0; mt < 4; ++mt) {
                int row = wm * 64 + mt * 16 + lo;
                af[mt] = *(const short8*)(lds + tap * 8192 + row * 64 + SWZ(quad, row) * 16);
            }
#pragma unroll
            for (int nt = 0; nt < 4; ++nt) {
                int pr = (wr + ky) * 68 + nt * 16 + lo + kx;
                short8 bf = *(const short8*)(Braw + pr * 64 + SWZ(quad, pr) * 16);
#pragma unroll
                for (int mt = 0; mt < 4; ++mt) acc[mt][nt] = MFMA16(af[mt], bf, acc[mt][nt]);
            }
        }
    }
#pragma unroll
    for (int mt = 0; mt < 4; ++mt)
#pragma unroll
        for (int nt = 0; nt < 4; ++nt) {
            int oo0 = wm * 64 + mt * 16 + quad * 4;
            int col = nt * 16 + lo;
            int sp = (y0 + wr) * 64 + col;
            size_t tbase = ((size_t)(b * 4096) + sp) * 128 + oo0;
            ushort4 mv = *(const ushort4*)(midT + tbase);
            ushort4 gv = *(const ushort4*)(g3T + tbase);
#pragma unroll
            for (int r = 0; r < 4; ++r) {
                int oo = oo0 + r;
                size_t off = ((size_t)(b * 128 + oo) << 12) + sp;
                out[off] = bf2f((&mv.x)[r]) * bf2f((&gv.x)[r]) + acc[mt][nt][r] + bias[oo];
            }
        }
}

// ===================== launch =====================
extern "C" void kernel_launch(void* const* d_in, const int* in_sizes, int n_in,
                              void* d_out, int out_size, void* d_ws, size_t ws_size,
                              hipStream_t stream)
{
    const float* x    = (const float*)d_in[0];
    const float* edge = (const float*)d_in[1];
    const float* seg  = (const float*)d_in[2];
    const float* pe   = (const float*)d_in[3];
    const float* ps   = (const float*)d_in[4];
    const float* q_w  = (const float*)d_in[5];  const float* q_b  = (const float*)d_in[6];
    const float* k_w  = (const float*)d_in[7];  const float* k_b  = (const float*)d_in[8];
    const float* v_w  = (const float*)d_in[9];  const float* v_b  = (const float*)d_in[10];
    const float* d1_ew = (const float*)d_in[11]; const float* d1_eb = (const float*)d_in[12];
    const float* d1_sw = (const float*)d_in[13]; const float* d1_sb = (const float*)d_in[14];
    const float* d1_bw = (const float*)d_in[15]; const float* d1_bb = (const float*)d_in[16];
    const float* d2_ew = (const float*)d_in[17]; const float* d2_eb = (const float*)d_in[18];
    const float* d2_sw = (const float*)d_in[19]; const float* d2_sb = (const float*)d_in[20];
    const float* d2_bw = (const float*)d_in[21]; const float* d2_bb = (const float*)d_in[22];
    const float* sc_w  = (const float*)d_in[23]; const float* sc_b  = (const float*)d_in[24];
    const float* bi1_w = (const float*)d_in[25]; const float* bi1_b = (const float*)d_in[26];
    const float* bi2_w = (const float*)d_in[27]; const float* bi2_b = (const float*)d_in[28];

    char* ws = (char*)d_ws;
    ushort_t* wb = (ushort_t*)ws;                         // 1,327,360
    ushort_t* wc = (ushort_t*)(ws + 1327360);             // 294,912
    float* bc    = (float*)(ws + 1622272);                // 2,048
    float* stats = (float*)(ws + 1624320);                // 512
    char* RA = ws + 1703936;                              // 37,748,736: auxT -> SP
    char* RB = RA + 37748736;                             // 16,777,216: xT
    char* RC = RB + 16777216;                             // 50,331,648: q0T/k0T/v0T -> midT+oT
    char* RD = RC + 50331648;                             // 16,777,216: g1 -> g3
    char* RE = RD + 16777216;                             // 16,777,216: betA1
    char* RF = RE + 16777216;                             // 16,777,216: g2
    char* RG = RF + 16777216;                             // 16,777,216: betA2
    char* RH = RG + 16777216;                             // 33,554,432: Qp,Kp
    char* RI = RH + 33554432;                             // 16,777,216: VT -> tT

    ushort_t* auxT = (ushort_t*)RA;
    ushort_t* SP0  = (ushort_t*)RA;
    ushort_t* xT   = (ushort_t*)RB;
    ushort_t* q0T  = (ushort_t*)RC;
    ushort_t* midT = (ushort_t*)RC;
    ushort_t* oT   = (ushort_t*)(RC + 16777216);
    ushort_t* g1   = (ushort_t*)RD;
    ushort_t* g3   = (ushort_t*)RD;
    ushort_t* betA1= (ushort_t*)RE;
    ushort_t* g2   = (ushort_t*)RF;
    ushort_t* betA2= (ushort_t*)RG;
    ushort_t* Qp   = (ushort_t*)RH;
    ushort_t* Kp   = Qp + 8388608;
    ushort_t* VT   = (ushort_t*)RI;
    ushort_t* tT   = (ushort_t*)RI;
    const size_t ZB = 8388608;

    dim3 blk(256);

    hipMemsetAsync(stats, 0, 512, stream);
    prep_w<<<2592, blk, 0, stream>>>(wb, q_w, k_w, v_w, d1_ew, d2_ew, d1_sw, d2_sw, d1_bw, d2_bw, sc_w, bi1_w, bi2_w);
    combine_bias<<<1, 512, 0, stream>>>(bc, d1_sw, d1_bw, d2_sw, d2_bw, d1_eb, d2_eb, d1_sb, d1_bb, d2_sb, d2_bb);
    combine_w<<<dim3(9, 4), blk, 0, stream>>>(wc, wb);
    transp_x<<<dim3(64, 16), blk, 0, stream>>>(x, xT);
    transp_aux<<<dim3(64, 16), blk, 0, stream>>>(edge, seg, pe, ps, auxT);

    // aux mega-GEMM fused: activations read once for all 4 slices
    gemm_stack<4, 0><<<dim3(32, 16), dim3(1024), 0, stream>>>(auxT, 288, wc, 9,
        B4{{bc, bc + 128, bc + 256, bc + 384}}, P4{{g1, betA1, g2, betA2}}, stats);
    // qkv fused: xT read once for q,k,v (+LN stats slots 0..2)
    gemm_stack<3, 1><<<dim3(32, 16), dim3(768), 0, stream>>>(xT, 128, wb, 4,
        B4{{q_b, k_b, v_b, nullptr}}, P4{{q0T, q0T + ZB, q0T + 2 * ZB, nullptr}}, stats);
    // ADN1 -> Qp, Kp, VT (K=128)
    gemm_conv<2><<<dim3(32, 16, 3), blk, 0, stream>>>(q0T, 128, ZB, wb + 155648, 256, 0, 4,
        B4{{nullptr, nullptr, nullptr, nullptr}}, P4{{Qp, Kp, VT, nullptr}}, g1, betA1, stats, 0);

    // attention
    gemm_attn<0><<<dim3(8, 8, 16), blk, 0, stream>>>(Qp, 262144, Kp, 262144, 256, 8, 0.0625f,
        SP0, 1048576, 1024, nullptr, nullptr, stats);
    gemm_attn<0><<<dim3(2, 2, 16), blk, 0, stream>>>(Qp + 4194304, 262144, Kp + 4194304, 262144, 1024, 32, 0.03125f,
        SP0 + 16777216, 65536, 256, nullptr, nullptr, stats);
    softmax_k<<<5120, blk, 0, stream>>>(SP0);
    gemm_attn<1><<<dim3(2, 8, 16), blk, 0, stream>>>(SP0, 1048576, VT, 262144, 1024, 32, 1.f,
        nullptr, 0, 0, xT, midT, stats);
    gemm_attn<2><<<dim3(8, 2, 16), blk, 0, stream>>>(SP0 + 16777216, 65536, VT + 4194304, 262144, 256, 8, 1.f,
        nullptr, 0, 0, xT, midT, stats);

    // ADN2 -> oT (K=128), quartered output layout
    gemm_conv<3><<<dim3(32, 16, 1), blk, 0, stream>>>(midT, 128, 0, wb + 155648 + 32768, 256, 0, 4,
        B4{{nullptr, nullptr, nullptr, nullptr}}, P4{{oT, nullptr, nullptr, nullptr}}, g2, betA2, stats, 0);

    // conv3x3 tail
    conv3x3_dual<<<dim3(8, 16, 2), dim3(1024), 0, stream>>>(oT, wb + 221184, wb + 368640, sc_b, bi1_b, g3, tT);
    conv3x3_final<<<dim3(16, 16), dim3(512), 0, stream>>>(tT, wb + 516096, bi2_b, (float*)d_out, midT, g3);
}

// Round 6
// 648.770 us; speedup vs baseline: 1.1331x; 1.1331x over previous
//
#include <hip/hip_runtime.h>
#include <cstdint>

typedef unsigned short ushort_t;
typedef unsigned int uint_t;
typedef __attribute__((ext_vector_type(8))) short short8;   // 8 bf16 (4 VGPRs) - MFMA A/B frag
typedef __attribute__((ext_vector_type(4))) float f32x4;    // MFMA C/D frag

#define MFMA16(a, b, c) __builtin_amdgcn_mfma_f32_16x16x32_bf16((a), (b), (c), 0, 0, 0)
#define SWZ(c, r) ((((c) + ((r) >> 2)) & 3))
#define INV_N 1.9073486328125e-6f  // 1/524288

struct P4 { ushort_t* p[4]; };
struct B4 { const float* b[4]; };

__device__ __forceinline__ ushort_t f2bf(float f) {
    uint_t u = __builtin_bit_cast(uint_t, f);
    u += 0x7FFFu + ((u >> 16) & 1u);          // RNE
    return (ushort_t)(u >> 16);
}
__device__ __forceinline__ float bf2f(ushort_t h) {
    return __builtin_bit_cast(float, (uint_t)h << 16);
}

// ===================== weight prep (same layout as round 4) =====================
__global__ __launch_bounds__(256) void prep_w(
    ushort_t* wb, const float* qw, const float* kw, const float* vw,
    const float* ew1, const float* ew2, const float* sw1, const float* sw2,
    const float* bw1, const float* bw2,
    const float* scw, const float* b1w, const float* b2w)
{
    int idx = blockIdx.x * 256 + threadIdx.x;
    if (idx >= 663552) return;
    float v;
    if (idx < 49152) {
        int z = idx >> 14, r = idx & 16383;
        v = (z == 0 ? qw : z == 1 ? kw : vw)[r];
    } else if (idx < 122880) {
        int j = idx - 49152; int z = j / 36864; int jj = j - z * 36864;
        int o = jj / 288, k = jj - o * 288;
        v = (k < 277) ? (z ? ew2 : ew1)[o * 277 + k] : 0.f;
    } else if (idx < 155648) {
        int j = idx - 122880; int z = j >> 14;
        v = (z ? sw2 : sw1)[j & 16383];
    } else if (idx < 221184) {
        int j = idx - 155648; int z = j >> 15;
        v = (z ? bw2 : bw1)[j & 32767];
    } else {
        int j = idx - 221184;
        const float* src = j < 147456 ? scw : j < 294912 ? b1w : b2w;
        j = j % 147456;
        int tap = j >> 14, r = (j >> 7) & 127, c = j & 127;
        v = src[r * 1152 + c * 9 + tap];
    }
    wb[idx] = f2bf(v);
}

// ===================== combined aux weights: wc[z][128][288] =====================
__global__ __launch_bounds__(256) void combine_w(ushort_t* wc, const ushort_t* wb)
{
    __shared__ float ews[128 * 33];
    __shared__ ushort_t Ws[128 * 130];
    int z = blockIdx.y, nt = blockIdx.x, n0 = nt * 32;
    int t = threadIdx.x;
    const ushort_t* wew = wb + 49152;
    const ushort_t* wsw = wb + 122880;
    const ushort_t* wbw = wb + 155648;
    const ushort_t* W; int wstr, wof;
    if (z == 0)      { W = wsw;         wstr = 128; wof = 0; }
    else if (z == 1) { W = wbw;         wstr = 256; wof = 128; }
    else if (z == 2) { W = wsw + 16384; wstr = 128; wof = 0; }
    else             { W = wbw + 32768; wstr = 256; wof = 128; }
    const ushort_t* E = wew + (z >= 2 ? 36864 : 0);
    for (int s = t; s < 16384; s += 256) {
        int c = s & 127, o = s >> 7;
        Ws[c * 130 + o] = W[o * wstr + wof + c];
    }
    for (int s = t; s < 4096; s += 256) {
        int c = s >> 5, n = s & 31;
        ews[c * 33 + n] = bf2f(E[c * 288 + n0 + n]);
    }
    __syncthreads();
    int o = t & 127, nh = t >> 7;
    float acc[16];
#pragma unroll
    for (int i = 0; i < 16; ++i) acc[i] = 0.f;
    for (int c = 0; c < 128; ++c) {
        float wv = bf2f(Ws[c * 130 + o]);
#pragma unroll
        for (int i = 0; i < 16; ++i) acc[i] += wv * ews[c * 33 + nh * 16 + i];
    }
#pragma unroll
    for (int i = 0; i < 16; ++i)
        wc[(size_t)(z * 128 + o) * 288 + n0 + nh * 16 + i] = f2bf(acc[i]);
}

// combined biases bc[z][128] (fp32, from original fp32 params)
__global__ __launch_bounds__(512) void combine_bias(
    float* bc, const float* sw1, const float* bw1, const float* sw2, const float* bw2,
    const float* eb1, const float* eb2, const float* sb1, const float* bb1,
    const float* sb2, const float* bb2)
{
    int t = threadIdx.x; int z = t >> 7, o = t & 127;
    const float* W; int wstr, wof; const float* eb; float add;
    if (z == 0)      { W = sw1; wstr = 128; wof = 0;   eb = eb1; add = sb1[o]; }
    else if (z == 1) { W = bw1; wstr = 256; wof = 128; eb = eb1; add = bb1[o]; }
    else if (z == 2) { W = sw2; wstr = 128; wof = 0;   eb = eb2; add = sb2[o]; }
    else             { W = bw2; wstr = 256; wof = 128; eb = eb2; add = bb2[o]; }
    float s = add;
    for (int c = 0; c < 128; ++c) s += W[o * wstr + wof + c] * eb[c];
    bc[t] = s;
}

// ===================== x transpose: f32 [b][128][4096] -> bf16 [b][4096][128] ==========
__global__ __launch_bounds__(256) void transp_x(const float* __restrict__ x, ushort_t* __restrict__ xT)
{
    __shared__ ushort_t tile[64 * 130];
    int b = blockIdx.y, p0 = blockIdx.x * 64;
    int t = threadIdx.x;
#pragma unroll
    for (int i = 0; i < 8; ++i) {
        int s = t + i * 256;
        int c = s >> 4, p4 = (s & 15) * 4;
        float4 f = *(const float4*)(x + ((size_t)(b * 128 + c) << 12) + p0 + p4);
        tile[(p4 + 0) * 130 + c] = f2bf(f.x);
        tile[(p4 + 1) * 130 + c] = f2bf(f.y);
        tile[(p4 + 2) * 130 + c] = f2bf(f.z);
        tile[(p4 + 3) * 130 + c] = f2bf(f.w);
    }
    __syncthreads();
#pragma unroll
    for (int i = 0; i < 4; ++i) {
        int s = t + i * 256;
        int p = s >> 4, c8 = (s & 15) * 8;
        ushort_t v[8];
#pragma unroll
        for (int e = 0; e < 8; ++e) v[e] = tile[p * 130 + c8 + e];
        uint4 ov = {(uint_t)v[0] | ((uint_t)v[1] << 16), (uint_t)v[2] | ((uint_t)v[3] << 16),
                    (uint_t)v[4] | ((uint_t)v[5] << 16), (uint_t)v[6] | ((uint_t)v[7] << 16)};
        *(uint4*)(xT + ((size_t)(b * 4096) + p0 + p) * 128 + c8) = ov;
    }
}

// ===================== aux concat+transpose -> bf16 [b][4096][288] ==========
__global__ __launch_bounds__(256) void transp_aux(const float* __restrict__ edge, const float* __restrict__ seg,
                                                  const float* __restrict__ pe, const float* __restrict__ ps,
                                                  ushort_t* __restrict__ auxT)
{
    __shared__ ushort_t tile[64 * 292];
    int b = blockIdx.y, p0 = blockIdx.x * 64;
    int t = threadIdx.x;
#pragma unroll
    for (int i = 0; i < 18; ++i) {
        int s = t + i * 256;
        int c = s >> 4, p4 = (s & 15) * 4;
        float4 f = {0.f, 0.f, 0.f, 0.f};
        if (c < 128)       f = *(const float4*)(edge + ((size_t)(b * 128 + c) << 12) + p0 + p4);
        else if (c < 256)  f = *(const float4*)(seg + ((size_t)(b * 128 + c - 128) << 12) + p0 + p4);
        else if (c == 256) f = *(const float4*)(pe + ((size_t)b << 12) + p0 + p4);
        else if (c < 277)  f = *(const float4*)(ps + ((size_t)(b * 20 + c - 257) << 12) + p0 + p4);
        tile[(p4 + 0) * 292 + c] = f2bf(f.x);
        tile[(p4 + 1) * 292 + c] = f2bf(f.y);
        tile[(p4 + 2) * 292 + c] = f2bf(f.z);
        tile[(p4 + 3) * 292 + c] = f2bf(f.w);
    }
    __syncthreads();
#pragma unroll
    for (int i = 0; i < 9; ++i) {
        int s = t + i * 256;
        int p = s / 36, c8 = (s % 36) * 8;
        ushort_t v[8];
#pragma unroll
        for (int e = 0; e < 8; ++e) v[e] = tile[p * 292 + c8 + e];
        uint4 ov = {(uint_t)v[0] | ((uint_t)v[1] << 16), (uint_t)v[2] | ((uint_t)v[3] << 16),
                    (uint_t)v[4] | ((uint_t)v[5] << 16), (uint_t)v[6] | ((uint_t)v[7] << 16)};
        *(uint4*)(auxT + ((size_t)(b * 4096) + p0 + p) * 288 + c8) = ov;
    }
}

// ===================== conv1x1-family MFMA GEMM =====================
// EP 0: v=acc+bias -> bf16 [b][p][128] (+stats slot z if dostats); coalesced LDS epilogue
// EP 2: ADN1: v=acc + betT + (tin-mu)*rstd*gT; patch scatter (unchanged)
// EP 3: ADN2: same math as EP2, QUARTERED out [b*4+cc][p][32] (for conv staging)
template <int EP>
__global__ __launch_bounds__(256) void gemm_conv(
    const ushort_t* bA, int Kb1, size_t zBoff,
    const ushort_t* wA, int wstride, int wAperZ, int NK,
    B4 bias4, P4 out4, const ushort_t* gT, const ushort_t* betT,
    float* stats, int dostats)
{
    constexpr int LDSZ = (EP == 2) ? 33792 : 34816;
    __shared__ char lds[LDSZ];
    int b = blockIdx.y, bx = blockIdx.x, z = blockIdx.z;
    int t = threadIdx.x, lane = t & 63, w = t >> 6;
    int wm = w & 1, wn = w >> 1, lo = lane & 15, quad = lane >> 4;
    const ushort_t* wAz = wA + (wAperZ ? (size_t)z * 128 * wstride : 0);
    const ushort_t* bAz = bA + (size_t)z * zBoff;
    ushort_t* outp = out4.p[z];
    size_t bbase = (size_t)b * 4096;
    int y0 = 0, x0 = 0;
    if (EP == 2) { y0 = (bx >> 1) * 4; x0 = (bx & 1) * 32; }

    f32x4 acc[4][4];
#pragma unroll
    for (int i = 0; i < 4; ++i)
#pragma unroll
        for (int j = 0; j < 4; ++j) acc[i][j] = (f32x4){0.f, 0.f, 0.f, 0.f};

    int r0 = t >> 2, c0 = t & 3, r1 = r0 + 64;
    int gp0, gp1;
    if (EP == 2) {
        gp0 = (y0 + (r0 >> 5)) * 64 + x0 + (r0 & 31);
        gp1 = (y0 + (r1 >> 5)) * 64 + x0 + (r1 & 31);
    } else {
        gp0 = bx * 128 + r0;
        gp1 = bx * 128 + r1;
    }
    const ushort_t* bRow0 = bAz + (bbase + gp0) * Kb1;
    const ushort_t* bRow1 = bAz + (bbase + gp1) * Kb1;
    uint4 pfA0 = *(const uint4*)(wAz + (size_t)r0 * wstride + c0 * 8);
    uint4 pfA1 = *(const uint4*)(wAz + (size_t)r1 * wstride + c0 * 8);
    uint4 pfB0 = *(const uint4*)(bRow0 + c0 * 8);
    uint4 pfB1 = *(const uint4*)(bRow1 + c0 * 8);
    for (int ck = 0; ck < NK; ++ck) {
        __syncthreads();
        *(uint4*)(lds + r0 * 64 + SWZ(c0, r0) * 16) = pfA0;
        *(uint4*)(lds + r1 * 64 + SWZ(c0, r1) * 16) = pfA1;
        *(uint4*)(lds + 8192 + r0 * 64 + SWZ(c0, r0) * 16) = pfB0;
        *(uint4*)(lds + 8192 + r1 * 64 + SWZ(c0, r1) * 16) = pfB1;
        __syncthreads();
        if (ck + 1 < NK) {
            int k0 = (ck + 1) * 32;
            pfA0 = *(const uint4*)(wAz + (size_t)r0 * wstride + k0 + c0 * 8);
            pfA1 = *(const uint4*)(wAz + (size_t)r1 * wstride + k0 + c0 * 8);
            pfB0 = *(const uint4*)(bRow0 + k0 + c0 * 8);
            pfB1 = *(const uint4*)(bRow1 + k0 + c0 * 8);
        }
        short8 af[4];
#pragma unroll
        for (int mt = 0; mt < 4; ++mt) {
            int row = wm * 64 + mt * 16 + lo;
            af[mt] = *(const short8*)(lds + row * 64 + SWZ(quad, row) * 16);
        }
#pragma unroll
        for (int nt = 0; nt < 4; ++nt) {
            int n = wn * 64 + nt * 16 + lo;
            short8 bf = *(const short8*)(lds + 8192 + n * 64 + SWZ(quad, n) * 16);
#pragma unroll
            for (int mt = 0; mt < 4; ++mt) acc[mt][nt] = MFMA16(af[mt], bf, acc[mt][nt]);
        }
    }

    float mean = 0.f, rstd = 0.f;
    if (EP >= 2) {
        int slot = (EP == 3) ? 3 : z;
        float s0 = stats[(slot * 16 + b) * 2], s1 = stats[(slot * 16 + b) * 2 + 1];
        mean = s0 * INV_N;
        rstd = rsqrtf(fmaxf(s1 * INV_N - mean * mean, 0.f) + 1e-5f);
    }
    float lsum = 0.f, lss = 0.f;
    if (EP == 2) {
        __syncthreads();
        ushort_t* Cs = (ushort_t*)lds;
#pragma unroll
        for (int mt = 0; mt < 4; ++mt)
#pragma unroll
            for (int nt = 0; nt < 4; ++nt) {
                int oo0 = wm * 64 + mt * 16 + quad * 4;
                int pp = wn * 64 + nt * 16 + lo;
                int gp = (y0 + (pp >> 5)) * 64 + x0 + (pp & 31);
                size_t tbase = (bbase + gp) * 128 + oo0;
                ushort4 tv = *(const ushort4*)(bAz + tbase);
                ushort4 gv = *(const ushort4*)(gT + tbase);
                ushort4 bv = *(const ushort4*)(betT + tbase);
#pragma unroll
                for (int r = 0; r < 4; ++r) {
                    float v = acc[mt][nt][r] + bf2f((&bv.x)[r])
                            + (bf2f((&tv.x)[r]) - mean) * rstd * bf2f((&gv.x)[r]);
                    Cs[(oo0 + r) * 132 + pp] = f2bf(v);
                }
            }
        __syncthreads();
        if (z < 2) {
            // half0 [n][256]: full 512B rows
            for (int s = t; s < 1024; s += 256) {
                int n_l = s >> 5, fq = s & 31;
                int ypair = n_l >> 4, xp = n_l & 15;
                ushort_t tmp[8];
#pragma unroll
                for (int e = 0; e < 8; ++e) {
                    int f = fq * 8 + e;
                    int c = f >> 2, py = (f >> 1) & 1, px = f & 1;
                    tmp[e] = Cs[c * 132 + (ypair * 2 + py) * 32 + xp * 2 + px];
                }
                int n = ((y0 >> 1) + ypair) * 32 + (x0 >> 1) + xp;
                uint4 ov = {(uint_t)tmp[0] | ((uint_t)tmp[1] << 16), (uint_t)tmp[2] | ((uint_t)tmp[3] << 16),
                            (uint_t)tmp[4] | ((uint_t)tmp[5] << 16), (uint_t)tmp[6] | ((uint_t)tmp[7] << 16)};
                *(uint4*)(outp + ((size_t)(b * 1024 + n) << 8) + fq * 8) = ov;
            }
            // half1 [n][1024]: full 2KB rows
            for (int s = t; s < 1024; s += 256) {
                int n_l = s >> 7, fq = s & 127;
                ushort_t tmp[8];
#pragma unroll
                for (int e = 0; e < 8; ++e) {
                    int f = fq * 8 + e;
                    int c = f >> 4, py = (f >> 2) & 3, px = f & 3;
                    tmp[e] = Cs[(64 + c) * 132 + py * 32 + n_l * 4 + px];
                }
                int n = (y0 >> 2) * 16 + (x0 >> 2) + n_l;
                uint4 ov = {(uint_t)tmp[0] | ((uint_t)tmp[1] << 16), (uint_t)tmp[2] | ((uint_t)tmp[3] << 16),
                            (uint_t)tmp[4] | ((uint_t)tmp[5] << 16), (uint_t)tmp[6] | ((uint_t)tmp[7] << 16)};
                *(uint4*)(outp + 4194304u + ((size_t)(b * 256 + n) << 10) + fq * 8) = ov;
            }
        } else {
            // VT half0 [f=256][m=1024]
            for (int s = t; s < 2048; s += 256) {
                int f = s >> 3, j = s & 7;
                int ypair = j >> 2, xq = j & 3;
                int c = f >> 2, py = (f >> 1) & 1, px = f & 1;
                ushort_t tmp[4];
#pragma unroll
                for (int i2 = 0; i2 < 4; ++i2)
                    tmp[i2] = Cs[c * 132 + (ypair * 2 + py) * 32 + (xq * 4 + i2) * 2 + px];
                int m0 = ((y0 >> 1) + ypair) * 32 + (x0 >> 1) + xq * 4;
                uint2 ov = {(uint_t)tmp[0] | ((uint_t)tmp[1] << 16), (uint_t)tmp[2] | ((uint_t)tmp[3] << 16)};
                *(uint2*)(outp + ((size_t)(b * 256 + f) << 10) + m0) = ov;
            }
            // VT half1 [f=1024][m=256]
            for (int s = t; s < 2048; s += 256) {
                int f = s >> 1, j = s & 1;
                int c = f >> 4, py = (f >> 2) & 3, px = f & 3;
                ushort_t tmp[4];
#pragma unroll
                for (int i2 = 0; i2 < 4; ++i2)
                    tmp[i2] = Cs[(64 + c) * 132 + py * 32 + (j * 4 + i2) * 4 + px];
                int m0 = (y0 >> 2) * 16 + (x0 >> 2) + j * 4;
                uint2 ov = {(uint_t)tmp[0] | ((uint_t)tmp[1] << 16), (uint_t)tmp[2] | ((uint_t)tmp[3] << 16)};
                *(uint2*)(outp + 4194304u + ((size_t)(b * 1024 + f) << 8) + m0) = ov;
            }
        }
    } else {
        // EP0 / EP3: stage C-tile in LDS as [pp][136ch] then copy out fully coalesced
        ushort_t* Cs = (ushort_t*)lds;
        __syncthreads();
#pragma unroll
        for (int mt = 0; mt < 4; ++mt)
#pragma unroll
            for (int nt = 0; nt < 4; ++nt) {
                int oo0 = wm * 64 + mt * 16 + quad * 4;
                int pp = wn * 64 + nt * 16 + lo;
                float vv[4];
                if (EP == 0) {
#pragma unroll
                    for (int r = 0; r < 4; ++r) vv[r] = acc[mt][nt][r] + bias4.b[z][oo0 + r];
                    if (dostats) {
#pragma unroll
                        for (int r = 0; r < 4; ++r) { lsum += vv[r]; lss += vv[r] * vv[r]; }
                    }
                } else {  // EP 3
                    size_t tbase = (bbase + bx * 128 + pp) * 128 + oo0;
                    ushort4 tv = *(const ushort4*)(bAz + tbase);
                    ushort4 gv = *(const ushort4*)(gT + tbase);
                    ushort4 bv = *(const ushort4*)(betT + tbase);
#pragma unroll
                    for (int r = 0; r < 4; ++r)
                        vv[r] = acc[mt][nt][r] + bf2f((&bv.x)[r])
                              + (bf2f((&tv.x)[r]) - mean) * rstd * bf2f((&gv.x)[r]);
                }
                ushort4 st = {f2bf(vv[0]), f2bf(vv[1]), f2bf(vv[2]), f2bf(vv[3])};
                *(ushort4*)(&Cs[pp * 136 + oo0]) = st;
            }
        __syncthreads();
        if (EP == 3) {
            // quartered out: [b*4+cc][4096][32]
#pragma unroll
            for (int i = 0; i < 2; ++i) {
                int c = t + i * 256;
                int cc2 = c >> 7, pp = c & 127;
                size_t dst = ((size_t)(b * 4 + cc2) * 4096 + bx * 128 + pp) * 32;
#pragma unroll
                for (int j = 0; j < 4; ++j)
                    *(uint4*)(outp + dst + j * 8) = *(const uint4*)(&Cs[pp * 136 + cc2 * 32 + j * 8]);
            }
        } else {
            int pp = t >> 1, hf = t & 1;
            size_t gofs = (bbase + bx * 128 + pp) * 128 + hf * 64;
#pragma unroll
            for (int i = 0; i < 8; ++i)
                *(uint4*)(outp + gofs + i * 8) = *(const uint4*)(&Cs[pp * 136 + hf * 64 + i * 8]);
        }
    }
    if (EP == 0 && dostats) {
#pragma unroll
        for (int o2 = 32; o2 >= 1; o2 >>= 1) { lsum += __shfl_xor(lsum, o2); lss += __shfl_xor(lss, o2); }
        __syncthreads();
        float* red = (float*)lds;
        if (lane == 0) { red[w * 2] = lsum; red[w * 2 + 1] = lss; }
        __syncthreads();
        if (t == 0) {
            atomicAdd(&stats[(z * 16 + b) * 2], red[0] + red[2] + red[4] + red[6]);
            atomicAdd(&stats[(z * 16 + b) * 2 + 1], red[1] + red[3] + red[5] + red[7]);
        }
    }
}

// ===================== attention batched MFMA GEMM ===============
// EP0 stages S through LDS (col-major) for fully coalesced row writes.
template <int EP>
__global__ __launch_bounds__(256) void gemm_attn(
    const ushort_t* A, size_t aBS, const ushort_t* Bm, size_t bBS,
    int Ka, int NK, float scale,
    ushort_t* sout, size_t soBS, int soNb,
    const ushort_t* xT, ushort_t* midT, float* stats)
{
    constexpr int LDSZ = (EP >= 1) ? 33792 : 34816;
    __shared__ char lds[LDSZ];
    int b = blockIdx.z, my = blockIdx.y, nx = blockIdx.x;
    int t = threadIdx.x, lane = t & 63, w = t >> 6;
    int wm = w & 1, wn = w >> 1, lo = lane & 15, quad = lane >> 4;

    f32x4 acc[4][4];
#pragma unroll
    for (int i = 0; i < 4; ++i)
#pragma unroll
        for (int j = 0; j < 4; ++j) acc[i][j] = (f32x4){0.f, 0.f, 0.f, 0.f};

    const ushort_t* Ab = A + b * aBS + (size_t)(my * 128) * Ka;
    const ushort_t* Bb = Bm + b * bBS + (size_t)(nx * 128) * Ka;
    int r0 = t >> 2, c0 = t & 3, r1 = r0 + 64;
    uint4 pfA0 = *(const uint4*)(Ab + (size_t)r0 * Ka + c0 * 8);
    uint4 pfA1 = *(const uint4*)(Ab + (size_t)r1 * Ka + c0 * 8);
    uint4 pfB0 = *(const uint4*)(Bb + (size_t)r0 * Ka + c0 * 8);
    uint4 pfB1 = *(const uint4*)(Bb + (size_t)r1 * Ka + c0 * 8);
    for (int ck = 0; ck < NK; ++ck) {
        __syncthreads();
        *(uint4*)(lds + r0 * 64 + SWZ(c0, r0) * 16) = pfA0;
        *(uint4*)(lds + r1 * 64 + SWZ(c0, r1) * 16) = pfA1;
        *(uint4*)(lds + 8192 + r0 * 64 + SWZ(c0, r0) * 16) = pfB0;
        *(uint4*)(lds + 8192 + r1 * 64 + SWZ(c0, r1) * 16) = pfB1;
        __syncthreads();
        if (ck + 1 < NK) {
            int k0 = (ck + 1) * 32;
            pfA0 = *(const uint4*)(Ab + (size_t)r0 * Ka + k0 + c0 * 8);
            pfA1 = *(const uint4*)(Ab + (size_t)r1 * Ka + k0 + c0 * 8);
            pfB0 = *(const uint4*)(Bb + (size_t)r0 * Ka + k0 + c0 * 8);
            pfB1 = *(const uint4*)(Bb + (size_t)r1 * Ka + k0 + c0 * 8);
        }
        short8 af[4];
#pragma unroll
        for (int mt = 0; mt < 4; ++mt) {
            int row = wm * 64 + mt * 16 + lo;
            af[mt] = *(const short8*)(lds + row * 64 + SWZ(quad, row) * 16);
        }
#pragma unroll
        for (int nt = 0; nt < 4; ++nt) {
            int n = wn * 64 + nt * 16 + lo;
            short8 bf = *(const short8*)(lds + 8192 + n * 64 + SWZ(quad, n) * 16);
#pragma unroll
            for (int mt = 0; mt < 4; ++mt) acc[mt][nt] = MFMA16(af[mt], bf, acc[mt][nt]);
        }
    }

    if (EP == 0) {
        // stage col-major: Cs[c][136 + r]
        ushort_t* Cs = (ushort_t*)lds;
        __syncthreads();
#pragma unroll
        for (int mt = 0; mt < 4; ++mt)
#pragma unroll
            for (int nt = 0; nt < 4; ++nt) {
                int rr0 = wm * 64 + mt * 16 + quad * 4;
                int cl = wn * 64 + nt * 16 + lo;
                ushort4 st = {f2bf(acc[mt][nt][0] * scale), f2bf(acc[mt][nt][1] * scale),
                              f2bf(acc[mt][nt][2] * scale), f2bf(acc[mt][nt][3] * scale)};
                *(ushort4*)(&Cs[cl * 136 + rr0]) = st;
            }
        __syncthreads();
        {
            int rr = t >> 1, hf = t & 1;
            size_t gbase = (size_t)b * soBS + (size_t)(my * 128 + rr) * soNb + nx * 128 + hf * 64;
#pragma unroll
            for (int i = 0; i < 8; ++i) {
                ushort_t e[8];
#pragma unroll
                for (int j = 0; j < 8; ++j) e[j] = Cs[(hf * 64 + i * 8 + j) * 136 + rr];
                uint4 ov = {(uint_t)e[0] | ((uint_t)e[1] << 16), (uint_t)e[2] | ((uint_t)e[3] << 16),
                            (uint_t)e[4] | ((uint_t)e[5] << 16), (uint_t)e[6] | ((uint_t)e[7] << 16)};
                *(uint4*)(sout + gbase + i * 8) = ov;
            }
        }
        return;
    }
    __syncthreads();
    ushort_t* Cs = (ushort_t*)lds;
#pragma unroll
    for (int mt = 0; mt < 4; ++mt)
#pragma unroll
        for (int nt = 0; nt < 4; ++nt)
#pragma unroll
            for (int reg = 0; reg < 4; ++reg) {
                int r_l = wm * 64 + mt * 16 + quad * 4 + reg;
                int c_l = wn * 64 + nt * 16 + lo;
                Cs[r_l * 132 + c_l] = f2bf(acc[mt][nt][reg]);
            }
    __syncthreads();
    float lsum = 0.f, lss = 0.f;
    for (int s = t; s < 4096; s += 256) {
        int sp, r_l, cbase, pybit, pxbit;
        if (EP == 1) {
            int sp_l = s >> 3, cj = s & 7;
            int y_l = sp_l >> 6, xv = sp_l & 63;
            r_l = (y_l >> 1) * 32 + (xv >> 1);
            sp = (my * 8 + y_l) * 64 + xv;
            cbase = nx * 32 + cj * 4;
            pybit = (y_l & 1) * 2 + (xv & 1);
            pxbit = 4;
        } else {
            int sp_l = s >> 1, cj = s & 1;
            int y_l = sp_l >> 6, xv = sp_l & 63;
            r_l = (y_l >> 2) * 16 + (xv >> 2);
            sp = (my * 32 + y_l) * 64 + xv;
            cbase = 64 + nx * 8 + cj * 4;
            pybit = (y_l & 3) * 4 + (xv & 3);
            pxbit = 16;
        }
        size_t base = ((size_t)(b * 4096) + sp) * 128 + cbase;
        ushort4 xv4 = *(const ushort4*)(xT + base);
        int c_l0 = (EP == 1) ? (cbase - nx * 32) * 4 + pybit : (cbase - 64 - nx * 8) * 16 + pybit;
        ushort_t o4[4];
#pragma unroll
        for (int ci = 0; ci < 4; ++ci) {
            float vm = bf2f(Cs[r_l * 132 + c_l0 + ci * pxbit]) + bf2f((&xv4.x)[ci]);
            o4[ci] = f2bf(vm);
            lsum += vm; lss += vm * vm;
        }
        ushort4 st = {o4[0], o4[1], o4[2], o4[3]};
        *(ushort4*)(midT + base) = st;
    }
#pragma unroll
    for (int o2 = 32; o2 >= 1; o2 >>= 1) { lsum += __shfl_xor(lsum, o2); lss += __shfl_xor(lss, o2); }
    __syncthreads();
    float* red = (float*)lds;
    if (lane == 0) { red[w * 2] = lsum; red[w * 2 + 1] = lss; }
    __syncthreads();
    if (t == 0) {
        atomicAdd(&stats[(3 * 16 + b) * 2], red[0] + red[2] + red[4] + red[6]);
        atomicAdd(&stats[(3 * 16 + b) * 2 + 1], red[1] + red[3] + red[5] + red[7]);
    }
}

// ===================== softmax (in-place bf16 S -> P) =====================
__global__ __launch_bounds__(256) void softmax_k(ushort_t* SP)
{
    int wid = blockIdx.x * 4 + (threadIdx.x >> 6);
    int lane = threadIdx.x & 63;
    ushort_t* row;
    int PL;
    if (wid < 16384) { row = SP + ((size_t)wid << 10); PL = 16; }
    else { int r2 = wid - 16384; row = SP + 16777216u + ((size_t)r2 << 8); PL = 4; }
    float v[16];
    float mx = -1e30f;
    for (int i = 0; i < PL; ++i) { v[i] = bf2f(row[lane + (i << 6)]); mx = fmaxf(mx, v[i]); }
#pragma unroll
    for (int o = 32; o >= 1; o >>= 1) mx = fmaxf(mx, __shfl_xor(mx, o));
    float sum = 0.f;
    for (int i = 0; i < PL; ++i) { v[i] = __expf(v[i] - mx); sum += v[i]; }
#pragma unroll
    for (int o = 32; o >= 1; o >>= 1) sum += __shfl_xor(sum, o);
    float inv = 1.f / sum;
    for (int i = 0; i < PL; ++i) row[lane + (i << 6)] = f2bf(v[i] * inv);
}

// ===================== conv3x3 dual (tanh DIL1 / gelu DIL2 via z) =====================
// input oT QUARTERED [b*4+cc][4096][32]; z=0 out (g3) [p][128]; z=1 out (tT) QUARTERED.
__global__ __launch_bounds__(1024) void conv3x3_dual(
    const ushort_t* __restrict__ inT, const ushort_t* __restrict__ wtA, const ushort_t* __restrict__ wtB,
    const float* __restrict__ biasA, const float* __restrict__ biasB,
    ushort_t* __restrict__ outA, ushort_t* __restrict__ outB)
{
    __shared__ char lds[73728 + 12 * 68 * 64];
    char* Braw = lds + 73728;
    int b = blockIdx.y, z = blockIdx.z;
    int dil = 1 + z;
    int NRr = 8 + 2 * dil;
    const ushort_t* wt = z ? wtB : wtA;
    const float* bias = z ? biasB : biasA;
    ushort_t* out = z ? outB : outA;
    int y0 = blockIdx.x * 8;
    int t = threadIdx.x, lane = t & 63, w = t >> 6;
    int wm = w & 1, wr = w >> 1, lo = lane & 15, quad = lane >> 4;

    f32x4 acc[4][4];
#pragma unroll
    for (int i = 0; i < 4; ++i)
#pragma unroll
        for (int j = 0; j < 4; ++j) acc[i][j] = (f32x4){0.f, 0.f, 0.f, 0.f};

    for (int cc = 0; cc < 4; ++cc) {
        if (cc) __syncthreads();
        for (int s = t; s < 4608; s += 1024) {
            int tap = s >> 9, r = (s >> 2) & 127, c = s & 3;
            uint4 v = *(const uint4*)(wt + ((size_t)(tap * 128 + r) << 7) + cc * 32 + c * 8);
            *(uint4*)(lds + tap * 8192 + r * 64 + SWZ(c, r) * 16) = v;
        }
        int NSLOT = NRr * 272;
        for (int s = t; s < NSLOT; s += 1024) {
            int c4 = s & 3;
            int pr = s >> 2;
            int xx = pr % 68, rr = pr / 68;
            int ys = y0 - dil + rr;
            int ix = xx - dil;
            uint4 v = {0u, 0u, 0u, 0u};
            if (ys >= 0 && ys < 64 && (unsigned)ix < 64u)
                v = *(const uint4*)(inT + ((size_t)((b * 4 + cc) * 4096 + ys * 64 + ix)) * 32 + c4 * 8);
            *(uint4*)(Braw + pr * 64 + SWZ(c4, pr) * 16) = v;
        }
        __syncthreads();
#pragma unroll
        for (int tap = 0; tap < 9; ++tap) {
            int ky = tap / 3, kx = tap % 3;
            short8 af[4];
#pragma unroll
            for (int mt = 0; mt < 4; ++mt) {
                int row = wm * 64 + mt * 16 + lo;
                af[mt] = *(const short8*)(lds + tap * 8192 + row * 64 + SWZ(quad, row) * 16);
            }
#pragma unroll
            for (int nt = 0; nt < 4; ++nt) {
                int pr = (wr + ky * dil) * 68 + nt * 16 + lo + kx * dil;
                short8 bf = *(const short8*)(Braw + pr * 64 + SWZ(quad, pr) * 16);
#pragma unroll
                for (int mt = 0; mt < 4; ++mt) acc[mt][nt] = MFMA16(af[mt], bf, acc[mt][nt]);
            }
        }
    }
    // coalesced epilogue: two halves of 4 rows each, staged in LDS then linear copy-out
    for (int h = 0; h < 2; ++h) {
        __syncthreads();
        if ((wr >> 2) == h) {
            int rl = wr & 3;
#pragma unroll
            for (int mt = 0; mt < 4; ++mt)
#pragma unroll
                for (int nt = 0; nt < 4; ++nt) {
                    int oo0 = wm * 64 + mt * 16 + quad * 4;
                    int col = nt * 16 + lo;
                    ushort4 st;
#pragma unroll
                    for (int r = 0; r < 4; ++r) {
                        float v = acc[mt][nt][r] + bias[oo0 + r];
                        if (z == 0) v = tanhf(v);
                        else        v = 0.5f * v * (1.f + erff(v * 0.70710678118654752f));
                        (&st.x)[r] = f2bf(v);
                    }
                    int byo = ((rl * 64 + col) * 256 + oo0 * 2) ^ ((col & 15) << 4);
                    *(ushort4*)(lds + byo) = st;
                }
        }
        __syncthreads();
        if (z == 0) {
            int rl2 = t >> 8, col2 = (t >> 2) & 63, k2 = t & 3;
            char* dst = (char*)out + (((size_t)(b * 4096) + (y0 + h * 4 + rl2) * 64 + col2) << 8) + k2 * 64;
            int bb = (rl2 * 64 + col2) * 256 + k2 * 64;
            int sw = (col2 & 15) << 4;
#pragma unroll
            for (int i = 0; i < 4; ++i)
                *(uint4*)(dst + i * 16) = *(const uint4*)(lds + ((bb + i * 16) ^ sw));
        } else {
            int cc2 = t >> 8, s_l = t & 255;
            int rl2 = s_l >> 6, col2 = s_l & 63;
            ushort_t* dst = out + ((size_t)((b * 4 + cc2) * 4096) + (y0 + h * 4 + rl2) * 64 + col2) * 32;
            int bb = (rl2 * 64 + col2) * 256 + cc2 * 64;
            int sw = (col2 & 15) << 4;
#pragma unroll
            for (int i = 0; i < 4; ++i)
                *(uint4*)(dst + i * 8) = *(const uint4*)(lds + ((bb + i * 16) ^ sw));
        }
    }
}

// ===================== conv3x3 final: midT*g3T + conv(tT) -> f32 [b][c][p] ==============
// input tT QUARTERED [b*4+cc][4096][32].
__global__ __launch_bounds__(512) void conv3x3_final(
    const ushort_t* __restrict__ inT, const ushort_t* __restrict__ wt, const float* __restrict__ bias,
    float* __restrict__ out, const ushort_t* __restrict__ midT, const ushort_t* __restrict__ g3T)
{
    __shared__ char lds[73728 + 6 * 68 * 64];
    char* Braw = lds + 73728;
    int b = blockIdx.y;
    int y0 = blockIdx.x * 4;
    int t = threadIdx.x, lane = t & 63, w = t >> 6;
    int wm = w & 1, wr = w >> 1, lo = lane & 15, quad = lane >> 4;

    f32x4 acc[4][4];
#pragma unroll
    for (int i = 0; i < 4; ++i)
#pragma unroll
        for (int j = 0; j < 4; ++j) acc[i][j] = (f32x4){0.f, 0.f, 0.f, 0.f};

    for (int cc = 0; cc < 4; ++cc) {
        if (cc) __syncthreads();
        for (int s = t; s < 4608; s += 512) {
            int tap = s >> 9, r = (s >> 2) & 127, c = s & 3;
            uint4 v = *(const uint4*)(wt + ((size_t)((tap)*128 + r) << 7) + cc * 32 + c * 8);
            *(uint4*)(lds + tap * 8192 + r * 64 + SWZ(c, r) * 16) = v;
        }
        for (int s = t; s < 1632; s += 512) {
            int c4 = s & 3;
            int pr = s >> 2;
            int xx = pr % 68, rr = pr / 68;
            int ys = y0 - 1 + rr;
            int ix = xx - 1;
            uint4 v = {0u, 0u, 0u, 0u};
            if (ys >= 0 && ys < 64 && (unsigned)ix < 64u)
                v = *(const uint4*)(inT + ((size_t)((b * 4 + cc) * 4096 + ys * 64 + ix)) * 32 + c4 * 8);
            *(uint4*)(Braw + pr * 64 + SWZ(c4, pr) * 16) = v;
        }
        __syncthreads();
#pragma unroll
        for (int tap = 0; tap < 9; ++tap) {
            int ky = tap / 3, kx = tap % 3;
            short8 af[4];
#pragma unroll
            for (int mt = 0; mt < 4; ++mt) {
                int row = wm * 64 + mt * 16 + lo;
                af[mt] = *(const short8*)(lds + tap * 8192 + row * 64 + SWZ(quad, row) * 16);
            }
#pragma unroll
            for (int nt = 0; nt < 4; ++nt) {
                int pr = (wr + ky) * 68 + nt * 16 + lo + kx;
                short8 bf = *(const short8*)(Braw + pr * 64 + SWZ(quad, pr) * 16);
#pragma unroll
                for (int mt = 0; mt < 4; ++mt) acc[mt][nt] = MFMA16(af[mt], bf, acc[mt][nt]);
            }
        }
    }
#pragma unroll
    for (int mt = 0; mt < 4; ++mt)
#pragma unroll
        for (int nt = 0; nt < 4; ++nt) {
            int oo0 = wm * 64 + mt * 16 + quad * 4;
            int col = nt * 16 + lo;
            int sp = (y0 + wr) * 64 + col;
            size_t tbase = ((size_t)(b * 4096) + sp) * 128 + oo0;
            ushort4 mv = *(const ushort4*)(midT + tbase);
            ushort4 gv = *(const ushort4*)(g3T + tbase);
#pragma unroll
            for (int r = 0; r < 4; ++r) {
                int oo = oo0 + r;
                size_t off = ((size_t)(b * 128 + oo) << 12) + sp;
                out[off] = bf2f((&mv.x)[r]) * bf2f((&gv.x)[r]) + acc[mt][nt][r] + bias[oo];
            }
        }
}

// ===================== launch =====================
extern "C" void kernel_launch(void* const* d_in, const int* in_sizes, int n_in,
                              void* d_out, int out_size, void* d_ws, size_t ws_size,
                              hipStream_t stream)
{
    const float* x    = (const float*)d_in[0];
    const float* edge = (const float*)d_in[1];
    const float* seg  = (const float*)d_in[2];
    const float* pe   = (const float*)d_in[3];
    const float* ps   = (const float*)d_in[4];
    const float* q_w  = (const float*)d_in[5];  const float* q_b  = (const float*)d_in[6];
    const float* k_w  = (const float*)d_in[7];  const float* k_b  = (const float*)d_in[8];
    const float* v_w  = (const float*)d_in[9];  const float* v_b  = (const float*)d_in[10];
    const float* d1_ew = (const float*)d_in[11]; const float* d1_eb = (const float*)d_in[12];
    const float* d1_sw = (const float*)d_in[13]; const float* d1_sb = (const float*)d_in[14];
    const float* d1_bw = (const float*)d_in[15]; const float* d1_bb = (const float*)d_in[16];
    const float* d2_ew = (const float*)d_in[17]; const float* d2_eb = (const float*)d_in[18];
    const float* d2_sw = (const float*)d_in[19]; const float* d2_sb = (const float*)d_in[20];
    const float* d2_bw = (const float*)d_in[21]; const float* d2_bb = (const float*)d_in[22];
    const float* sc_w  = (const float*)d_in[23]; const float* sc_b  = (const float*)d_in[24];
    const float* bi1_w = (const float*)d_in[25]; const float* bi1_b = (const float*)d_in[26];
    const float* bi2_w = (const float*)d_in[27]; const float* bi2_b = (const float*)d_in[28];

    char* ws = (char*)d_ws;
    ushort_t* wb = (ushort_t*)ws;                         // 1,327,360
    ushort_t* wc = (ushort_t*)(ws + 1327360);             // 294,912
    float* bc    = (float*)(ws + 1622272);                // 2,048
    float* stats = (float*)(ws + 1624320);                // 512
    char* RA = ws + 1703936;                              // 37,748,736: auxT -> SP
    char* RB = RA + 37748736;                             // 16,777,216: xT
    char* RC = RB + 16777216;                             // 50,331,648: q0T/k0T/v0T -> midT+oT
    char* RD = RC + 50331648;                             // 16,777,216: g1 -> g3
    char* RE = RD + 16777216;                             // 16,777,216: betA1
    char* RF = RE + 16777216;                             // 16,777,216: g2
    char* RG = RF + 16777216;                             // 16,777,216: betA2
    char* RH = RG + 16777216;                             // 33,554,432: Qp,Kp
    char* RI = RH + 33554432;                             // 16,777,216: VT -> tT

    ushort_t* auxT = (ushort_t*)RA;
    ushort_t* SP0  = (ushort_t*)RA;
    ushort_t* xT   = (ushort_t*)RB;
    ushort_t* q0T  = (ushort_t*)RC;
    ushort_t* midT = (ushort_t*)RC;
    ushort_t* oT   = (ushort_t*)(RC + 16777216);
    ushort_t* g1   = (ushort_t*)RD;
    ushort_t* g3   = (ushort_t*)RD;
    ushort_t* betA1= (ushort_t*)RE;
    ushort_t* g2   = (ushort_t*)RF;
    ushort_t* betA2= (ushort_t*)RG;
    ushort_t* Qp   = (ushort_t*)RH;
    ushort_t* Kp   = Qp + 8388608;
    ushort_t* VT   = (ushort_t*)RI;
    ushort_t* tT   = (ushort_t*)RI;
    const size_t ZB = 8388608;

    dim3 blk(256);

    hipMemsetAsync(stats, 0, 512, stream);
    prep_w<<<2592, blk, 0, stream>>>(wb, q_w, k_w, v_w, d1_ew, d2_ew, d1_sw, d2_sw, d1_bw, d2_bw, sc_w, bi1_w, bi2_w);
    combine_bias<<<1, 512, 0, stream>>>(bc, d1_sw, d1_bw, d2_sw, d2_bw, d1_eb, d2_eb, d1_sb, d1_bb, d2_sb, d2_bb);
    combine_w<<<dim3(9, 4), blk, 0, stream>>>(wc, wb);
    transp_x<<<dim3(64, 16), blk, 0, stream>>>(x, xT);
    transp_aux<<<dim3(64, 16), blk, 0, stream>>>(edge, seg, pe, ps, auxT);

    // aux mega-GEMM: g1, betA1, g2, betA2  (REVERTED: gemm_stack fusion regressed, r5)
    gemm_conv<0><<<dim3(32, 16, 4), blk, 0, stream>>>(auxT, 288, 0, wc, 288, 1, 9,
        B4{{bc, bc + 128, bc + 256, bc + 384}}, P4{{g1, betA1, g2, betA2}}, nullptr, nullptr, stats, 0);
    // qkv (+LN stats slots 0..2)
    gemm_conv<0><<<dim3(32, 16, 3), blk, 0, stream>>>(xT, 128, 0, wb, 128, 1, 4,
        B4{{q_b, k_b, v_b, nullptr}}, P4{{q0T, q0T + ZB, q0T + 2 * ZB, nullptr}}, nullptr, nullptr, stats, 1);
    // ADN1 -> Qp, Kp, VT (K=128)
    gemm_conv<2><<<dim3(32, 16, 3), blk, 0, stream>>>(q0T, 128, ZB, wb + 155648, 256, 0, 4,
        B4{{nullptr, nullptr, nullptr, nullptr}}, P4{{Qp, Kp, VT, nullptr}}, g1, betA1, stats, 0);

    // attention
    gemm_attn<0><<<dim3(8, 8, 16), blk, 0, stream>>>(Qp, 262144, Kp, 262144, 256, 8, 0.0625f,
        SP0, 1048576, 1024, nullptr, nullptr, stats);
    gemm_attn<0><<<dim3(2, 2, 16), blk, 0, stream>>>(Qp + 4194304, 262144, Kp + 4194304, 262144, 1024, 32, 0.03125f,
        SP0 + 16777216, 65536, 256, nullptr, nullptr, stats);
    softmax_k<<<5120, blk, 0, stream>>>(SP0);
    gemm_attn<1><<<dim3(2, 8, 16), blk, 0, stream>>>(SP0, 1048576, VT, 262144, 1024, 32, 1.f,
        nullptr, 0, 0, xT, midT, stats);
    gemm_attn<2><<<dim3(8, 2, 16), blk, 0, stream>>>(SP0 + 16777216, 65536, VT + 4194304, 262144, 256, 8, 1.f,
        nullptr, 0, 0, xT, midT, stats);

    // ADN2 -> oT (K=128), quartered output layout
    gemm_conv<3><<<dim3(32, 16, 1), blk, 0, stream>>>(midT, 128, 0, wb + 155648 + 32768, 256, 0, 4,
        B4{{nullptr, nullptr, nullptr, nullptr}}, P4{{oT, nullptr, nullptr, nullptr}}, g2, betA2, stats, 0);

    // conv3x3 tail
    conv3x3_dual<<<dim3(8, 16, 2), dim3(1024), 0, stream>>>(oT, wb + 221184, wb + 368640, sc_b, bi1_b, g3, tT);
    conv3x3_final<<<dim3(16, 16), dim3(512), 0, stream>>>(tT, wb + 516096, bi2_b, (float*)d_out, midT, g3);
}